// Round 5
// baseline (377.427 us; speedup 1.0000x reference)
//
#include <hip/hip_runtime.h>
#include <math.h>

// Problem constants (match reference)
#define B_ROWS 2048
#define V_COLS 32000
#define SCALE_D 30.0
#define COS_MARGIN_D 0.35
#define ARC_MARGIN_D 0.5
#define EPS_D 1e-12
#define PI_D 3.14159265358979323846

// exp(SCALE*x) = exp2(x * 30*log2(e)); arg range +/-43.3 -> raw v_exp_f32 ok.
#define LOG2E_X30 43.2808512266689022212f

typedef float f32x4 __attribute__((ext_vector_type(4)));

// R13: DRAM access-shape experiment. All prior kernels (both sessions,
// ~325us plateau) present ~512 concurrent scattered row-streams; the
// 6.6 TB/s poison fill sweeps ONE contiguous lockstep front. This kernel
// mimics the fill: 4KB chunks, block b takes chunks b, b+GRID, b+2*GRID...
// so the whole chip reads an ~8MB contiguous window marching linearly.
// Per-row sums via wave-level reduce (a wave's 256 contiguous floats touch
// <=2 rows; boundary waves ~3% take a second reduce+atomic) into fp64
// rowsum[2048] atomics. No LDS, no barriers.
#define TPB 256
#define GRID 2048
#define NV4_TOTAL (B_ROWS * (V_COLS / 4))   // 16,384,000 f32x4
#define NCHUNK (NV4_TOTAL / TPB)            // 64,000 chunks of 4KB

#define EXP30(x) __builtin_amdgcn_exp2f((x) * LOG2E_X30)

__global__ __launch_bounds__(TPB) void cosarc_sweep_kernel(
    const float* __restrict__ preds,
    double*      __restrict__ rowsum)
{
    const int b   = blockIdx.x;
    const int tid = threadIdx.x;
    const f32x4* p4 = (const f32x4*)preds;

    int c = b;
    f32x4 cur = __builtin_nontemporal_load(&p4[(size_t)c * TPB + tid]);

    for (int cn = c + GRID; ; cn += GRID) {
        const bool more = (cn < NCHUNK);
        f32x4 nxt = {0.f, 0.f, 0.f, 0.f};
        if (more) nxt = __builtin_nontemporal_load(&p4[(size_t)cn * TPB + tid]);

        // ---- process chunk c (data in cur) ----
        {
            const int base_f = c * (TPB * 4) + tid * 4;          // float idx of cur.x
            const int wave_f = c * (TPB * 4) + (tid & ~63) * 4;  // wave's first float
            const int r0 = wave_f / V_COLS;                      // wave-uniform row
            const int rA = base_f / V_COLS;                      // my elem0's row
            const int k  = min(4, V_COLS * (rA + 1) - base_f);   // my elems in row rA (1..4)

            const float e0 = EXP30(cur.x);
            const float e1 = EXP30(cur.y);
            const float e2 = EXP30(cur.z);
            const float e3 = EXP30(cur.w);

            float sA = e0;
            sA += (k > 1) ? e1 : 0.f;
            sA += (k > 2) ? e2 : 0.f;
            sA += (k > 3) ? e3 : 0.f;
            const float sB = ((k <= 1) ? e1 : 0.f) +
                             ((k <= 2) ? e2 : 0.f) +
                             ((k <= 3) ? e3 : 0.f);

            float clo = (rA == r0) ? sA : 0.f;
            float chi = (rA == r0) ? sB : sA;  // lanes fully past the boundary have sB==0

            // wave-uniform: does this wave's 256-float span cross a row boundary?
            const bool span = ((wave_f + 64 * 4 - 1) / V_COLS) != r0;

            #pragma unroll
            for (int off = 32; off > 0; off >>= 1)
                clo += __shfl_down(clo, off, 64);
            if (span) {
                #pragma unroll
                for (int off = 32; off > 0; off >>= 1)
                    chi += __shfl_down(chi, off, 64);
            }
            if ((tid & 63) == 0) {
                atomicAdd(&rowsum[r0], (double)clo);
                if (span) atomicAdd(&rowsum[r0 + 1], (double)chi);
            }
        }

        if (!more) break;
        cur = nxt;
        c = cn;
    }
}

// Finalize: per-row fp64 tail math + mean. One 1024-thread block; 2 rows
// per thread. Target gather is 2048 scattered 4B reads (latency ~2us).
__global__ __launch_bounds__(1024) void cosarc_final_kernel(
    const float*  __restrict__ preds,
    const int*    __restrict__ labels,
    const double* __restrict__ rowsum,
    float*        __restrict__ out)
{
    const int tid = threadIdx.x;
    double acc = 0.0;

    for (int r = tid; r < B_ROWS; r += 1024) {
        const float tgt_f = preds[(size_t)r * V_COLS + labels[r]];
        // subtract the same fp32 exp term that was accumulated for the target
        const double sum_others = rowsum[r] - (double)EXP30(tgt_f);

        double t = (double)tgt_f;
        t = fmin(fmax(t, -1.0 + EPS_D), 1.0 - EPS_D);
        double theta = acos(t);
        theta = fmin(fmax(theta, EPS_D), PI_D - EPS_D);
        const double numerator = SCALE_D * (cos(theta + ARC_MARGIN_D) - COS_MARGIN_D);
        const double denominator = exp(numerator) + sum_others;
        acc += numerator - log(denominator);
    }

    #pragma unroll
    for (int off = 32; off > 0; off >>= 1)
        acc += __shfl_down(acc, off, 64);

    __shared__ double wave_sums[16];
    if ((tid & 63) == 0) wave_sums[tid >> 6] = acc;
    __syncthreads();

    if (tid == 0) {
        double total = 0.0;
        #pragma unroll
        for (int w = 0; w < 16; ++w) total += wave_sums[w];
        out[0] = (float)(-(total / (double)B_ROWS));
    }
}

extern "C" void kernel_launch(void* const* d_in, const int* in_sizes, int n_in,
                              void* d_out, int out_size, void* d_ws, size_t ws_size,
                              hipStream_t stream)
{
    const float* preds  = (const float*)d_in[0];
    const int*   labels = (const int*)d_in[1];
    float*       out    = (float*)d_out;
    double*      rowsum = (double*)d_ws;   // 2048 * 8 B = 16 KB

    // rowsum must start at zero (workspace is poisoned by the harness)
    hipMemsetAsync(rowsum, 0, B_ROWS * sizeof(double), stream);

    cosarc_sweep_kernel<<<GRID, TPB, 0, stream>>>(preds, rowsum);
    cosarc_final_kernel<<<1, 1024, 0, stream>>>(preds, labels, rowsum, out);
}

// Round 6
// 323.502 us; speedup vs baseline: 1.1667x; 1.1667x over previous
//
#include <hip/hip_runtime.h>
#include <math.h>

// Problem constants (match reference)
#define B_ROWS 2048
#define V_COLS 32000
#define SCALE_D 30.0
#define COS_MARGIN_D 0.35
#define ARC_MARGIN_D 0.5
#define EPS_D 1e-12
#define PI_D 3.14159265358979323846

// exp(SCALE*x) = exp2(x * 30*log2(e)); arg range +/-43.3 -> raw v_exp_f32 ok.
#define LOG2E_X30 43.2808512266689022212f

typedef float f32x4 __attribute__((ext_vector_type(4)));

#define TPB 256  // one block per row; 4 waves/block, 8 blocks/CU -> 32 waves/CU

#define NT(p) __builtin_nontemporal_load(&(p))
#define EXP30(x) __builtin_amdgcn_exp2f((x) * LOG2E_X30)

// R14: temporal access-shape experiment. Every 6+ TB/s proof on this chip
// (poison fill 6.6, m13 copy 6.3, m146 rmsnorm 4.9) is a LONG-LIVED
// grid-stride streamer: waves issue hundreds of memory ops in continuous
// steady state. All our ~1.7 TB/s readers used short-lived waves (one
// 2-8-deep burst, then drain and exit) or serialized loops. R14 gives each
// wave a 31-iteration row stream with a 4-slot circular software pipeline
// (static slot indices, consume one / reload one 4 ahead) -> 4 loads/wave
// in flight SUSTAINED, 128 KB/CU continuously. nt loads kept (cached cost
// +25us in R11). ~45 VGPR, under the 64-VGPR occupancy cliff.
__global__ __launch_bounds__(TPB) void cosarc_row_kernel(
    const float* __restrict__ preds,
    const int*   __restrict__ labels,
    float*       __restrict__ row_terms)
{
    const int row = blockIdx.x;
    const int tid = threadIdx.x;
    const float* rowp = preds + (size_t)row * V_COLS;
    const f32x4* p4 = (const f32x4*)rowp;
    // 8000 f32x4 per row = 31 full 256-thread iterations (7936) + 64-thread tail

    // prologue: fill the 4-slot pipeline + issue the tail load early
    f32x4 b0 = NT(p4[0 * TPB + tid]);
    f32x4 b1 = NT(p4[1 * TPB + tid]);
    f32x4 b2 = NT(p4[2 * TPB + tid]);
    f32x4 b3 = NT(p4[3 * TPB + tid]);
    const bool hastail = (tid < (V_COLS / 4 - 31 * TPB));  // tid < 64
    f32x4 bt = {0.f, 0.f, 0.f, 0.f};
    if (hastail) bt = NT(p4[31 * TPB + tid]);

    float sx = 0.f, sy = 0.f, sz = 0.f, sw = 0.f;
#define CONSUME(v)                                                   \
    do {                                                             \
        sx += EXP30((v).x); sy += EXP30((v).y);                      \
        sz += EXP30((v).z); sw += EXP30((v).w);                      \
    } while (0)

    // steady state: consume slot, reload it 4 iterations ahead.
    // k = 0,4,8,12,16,20 -> consumes iters 0..23, loads iters 4..27.
    for (int k = 0; k + 8 <= 31; k += 4) {
        CONSUME(b0); b0 = NT(p4[(k + 4) * TPB + tid]);
        CONSUME(b1); b1 = NT(p4[(k + 5) * TPB + tid]);
        CONSUME(b2); b2 = NT(p4[(k + 6) * TPB + tid]);
        CONSUME(b3); b3 = NT(p4[(k + 7) * TPB + tid]);
    }
    // epilogue: b0..b3 hold iters 24..27; reload 28..30 while consuming.
    CONSUME(b0); b0 = NT(p4[28 * TPB + tid]);
    CONSUME(b1); b1 = NT(p4[29 * TPB + tid]);
    CONSUME(b2); b2 = NT(p4[30 * TPB + tid]);
    CONSUME(b3);
    CONSUME(b0); CONSUME(b1); CONSUME(b2);
    if (hastail) CONSUME(bt);
#undef CONSUME

    double sum = (double)((sx + sy) + (sz + sw));

    // wave(64) shuffle reduction in fp64
    #pragma unroll
    for (int off = 32; off > 0; off >>= 1)
        sum += __shfl_down(sum, off, 64);

    __shared__ double wave_sums[TPB / 64];
    const int wave = tid >> 6;
    const int lane = tid & 63;
    if (lane == 0) wave_sums[wave] = sum;
    __syncthreads();

    if (tid == 0) {
        double total = 0.0;
        #pragma unroll
        for (int w = 0; w < TPB / 64; ++w) total += wave_sums[w];

        const float tgt_f = rowp[labels[row]];
        // subtract the same fp32 exp term that was accumulated for the target
        const double sum_others = total - (double)EXP30(tgt_f);

        double t = (double)tgt_f;
        t = fmin(fmax(t, -1.0 + EPS_D), 1.0 - EPS_D);
        double theta = acos(t);
        theta = fmin(fmax(theta, EPS_D), PI_D - EPS_D);
        const double numerator = SCALE_D * (cos(theta + ARC_MARGIN_D) - COS_MARGIN_D);
        const double denominator = exp(numerator) + sum_others;
        row_terms[row] = (float)(numerator - log(denominator));
    }
}

// Reduce the 2048 per-row terms to -mean.
__global__ __launch_bounds__(256) void cosarc_reduce_kernel(
    const float* __restrict__ row_terms,
    float*       __restrict__ out)
{
    const int tid = threadIdx.x;
    double s = 0.0;
    for (int i = tid; i < B_ROWS; i += 256)
        s += (double)row_terms[i];

    #pragma unroll
    for (int off = 32; off > 0; off >>= 1)
        s += __shfl_down(s, off, 64);

    __shared__ double wave_sums[4];
    if ((tid & 63) == 0) wave_sums[tid >> 6] = s;
    __syncthreads();

    if (tid == 0) {
        double total = wave_sums[0] + wave_sums[1] + wave_sums[2] + wave_sums[3];
        out[0] = (float)(-(total / (double)B_ROWS));
    }
}

extern "C" void kernel_launch(void* const* d_in, const int* in_sizes, int n_in,
                              void* d_out, int out_size, void* d_ws, size_t ws_size,
                              hipStream_t stream)
{
    const float* preds  = (const float*)d_in[0];
    const int*   labels = (const int*)d_in[1];
    float*       out    = (float*)d_out;
    float*       ws     = (float*)d_ws;   // needs B_ROWS*4 = 8 KB

    cosarc_row_kernel<<<B_ROWS, TPB, 0, stream>>>(preds, labels, ws);
    cosarc_reduce_kernel<<<1, 256, 0, stream>>>(ws, out);
}